// Round 3
// baseline (1441.205 us; speedup 1.0000x reference)
//
#include <hip/hip_runtime.h>
#include <hip/hip_bf16.h>

#define KS 5
#define K3 125
#define NHIST (K3 * 32)
#define TILE 64
#define PADW 65

// ---------------------------------------------------------------------------
// Spline basis per (edge, s): basis[e*8+s], widx[e*8+s]
// ---------------------------------------------------------------------------
__global__ void basis_kernel(const float* __restrict__ pseudo,
                             float* __restrict__ basis, int* __restrict__ widx,
                             int E) {
    int e = blockIdx.x * blockDim.x + threadIdx.x;
    if (e >= E) return;
    float fr[3];
    int bot[3];
#pragma unroll
    for (int d = 0; d < 3; ++d) {
        float v = pseudo[e * 3 + d] * (float)(KS - 1);
        float fl = fminf(floorf(v), (float)(KS - 2));
        fr[d] = v - fl;
        bot[d] = (int)fl;
    }
    const int strides[3] = {1, KS, KS * KS};
#pragma unroll
    for (int s = 0; s < 8; ++s) {
        float b = 1.f;
        int w = 0;
#pragma unroll
        for (int d = 0; d < 3; ++d) {
            int bit = (s >> d) & 1;
            b *= bit ? fr[d] : (1.f - fr[d]);
            w += (bot[d] + bit) * strides[d];
        }
        basis[e * 8 + s] = b;
        widx[e * 8 + s] = w;
    }
}

__global__ void deg_kernel(const int* __restrict__ dst, float* __restrict__ deg, int E) {
    int e = blockIdx.x * blockDim.x + threadIdx.x;
    if (e >= E) return;
    atomicAdd(&deg[dst[e]], 1.0f);
}

// ---------------------------------------------------------------------------
// Counting sort by k with per-bucket padding to TILE. 32 sub-counters per k.
// hist and scatter use the identical p -> (tid&31) sub-counter mapping.
// ---------------------------------------------------------------------------
__global__ void hist_kernel(const int* __restrict__ widx, int* __restrict__ hist, int P) {
    int p = blockIdx.x * blockDim.x + threadIdx.x;
    if (p >= P) return;
    atomicAdd(&hist[widx[p] * 32 + (threadIdx.x & 31)], 1);
}

// Single block, 128 threads. Computes padded bucket bases, sub-counter
// cursors, and the tile->k map. tileOf must be pre-memset to -1.
__global__ void scan_pad_kernel(const int* __restrict__ hist, int* __restrict__ cur,
                                int* __restrict__ tileOf) {
    __shared__ int sh[128];
    int k = threadIdx.x;
    int cnt = 0;
    if (k < K3)
        for (int j = 0; j < 32; ++j) cnt += hist[k * 32 + j];
    int tiles = (cnt + TILE - 1) / TILE;
    sh[k] = tiles;
    __syncthreads();
    for (int d = 1; d < 128; d <<= 1) {
        int v = (k >= d) ? sh[k - d] : 0;
        __syncthreads();
        sh[k] += v;
        __syncthreads();
    }
    int tb = sh[k] - tiles;  // exclusive prefix in tiles
    if (k < K3) {
        int run = tb * TILE;
        for (int j = 0; j < 32; ++j) {
            cur[k * 32 + j] = run;
            run += hist[k * 32 + j];
        }
        for (int t = 0; t < tiles; ++t) tileOf[tb + t] = k;
    }
}

__global__ void scatter_kernel(const int* __restrict__ widx, int* __restrict__ cur,
                               int* __restrict__ sorted, int* __restrict__ posOf, int P) {
    int p = blockIdx.x * blockDim.x + threadIdx.x;
    if (p >= P) return;
    int pos = atomicAdd(&cur[widx[p] * 32 + (threadIdx.x & 31)], 1);
    sorted[pos] = p;
    posOf[p] = pos;
}

// ---------------------------------------------------------------------------
// GEMV over k-uniform tiles of 64 pairs. lane = pair. x-tile staged in LDS
// transposed (basis-prescaled). W[k] read via wave-uniform indices -> scalar
// loads, broadcast through the SGPR operand of v_fmac. y written coalesced
// via LDS transpose (reusing the xT buffer after the i-loops complete).
// 2 waves / block (LDS 2 * max(IN_C,32) * PADW floats).
// ---------------------------------------------------------------------------
template <int IN_C, int OUT_C>
__global__ __launch_bounds__(128) void gemv_k(
    const float* __restrict__ x, const int* __restrict__ src,
    const float* __restrict__ basis, const int* __restrict__ sorted,
    const int* __restrict__ tileOf, const float* __restrict__ W,
    float* __restrict__ y, int chunkBase, int chunkEnd) {
    constexpr int XROWS = (IN_C > 32) ? IN_C : 32;
    __shared__ float lds[2 * XROWS * PADW];
    const int wid = threadIdx.x >> 6;
    const int m = threadIdx.x & 63;
    float* xT = &lds[wid * XROWS * PADW];
    int t = chunkBase + blockIdx.x * 2 + wid;
    if (t >= chunkEnd) return;
    int k = tileOf[t];
    if (k < 0) return;
    k = __builtin_amdgcn_readfirstlane(k);
    int p = sorted[t * TILE + m];
    int e = p >> 3;
    float b = (p >= 0) ? basis[p] : 0.f;
    int sn = (p >= 0) ? src[e] : 0;
    // stage xT[i][r] = x[src_r][i] * b_r
    constexpr int RPI = 64 / IN_C;  // rows stored per iteration
    const int i0 = m % IN_C;
    const int rofs = m / IN_C;
    for (int r = rofs; r < TILE; r += RPI) {
        int sr = __shfl(sn, r);
        float br = __shfl(b, r);
        xT[i0 * PADW + r] = x[(size_t)sr * IN_C + i0] * br;
    }
    // wave-private LDS region; wave-synchronous, no barrier needed
    float acc[OUT_C];
    const float* __restrict__ Wk = W + (size_t)k * IN_C * OUT_C;
#pragma unroll
    for (int och = 0; och < OUT_C / 32; ++och) {
        float a[32];
#pragma unroll
        for (int oo = 0; oo < 32; ++oo) a[oo] = 0.f;
        for (int i = 0; i < IN_C; ++i) {
            float xv = xT[i * PADW + m];
#pragma unroll
            for (int oo = 0; oo < 32; ++oo)
                a[oo] = fmaf(Wk[i * OUT_C + och * 32 + oo], xv, a[oo]);
        }
#pragma unroll
        for (int oo = 0; oo < 32; ++oo) acc[och * 32 + oo] = a[oo];
    }
    // epilogue: coalesced y stores via LDS transpose (xT now dead)
    float* ysc = xT;
    float4* yrow = (float4*)(y + (size_t)(t - chunkBase) * TILE * OUT_C);
    const int c4 = m & 7, rr = m >> 3;
#pragma unroll
    for (int och = 0; och < OUT_C / 32; ++och) {
#pragma unroll
        for (int oo = 0; oo < 32; ++oo) ysc[oo * PADW + m] = acc[och * 32 + oo];
#pragma unroll
        for (int it = 0; it < 8; ++it) {
            int r = rr + it * 8;
            float4 v;
            v.x = ysc[(c4 * 4 + 0) * PADW + r];
            v.y = ysc[(c4 * 4 + 1) * PADW + r];
            v.z = ysc[(c4 * 4 + 2) * PADW + r];
            v.w = ysc[(c4 * 4 + 3) * PADW + r];
            yrow[(size_t)r * (OUT_C / 4) + och * 8 + c4] = v;
        }
    }
}

// ---------------------------------------------------------------------------
// Phase B: per edge, sum its (in-chunk) pair rows from y, one atomicAdd per
// output dword per edge (R1-proven cheap).
// ---------------------------------------------------------------------------
template <int OUT_C>
__global__ __launch_bounds__(256) void phaseB(
    const int* __restrict__ dst, const int* __restrict__ posOf,
    const float* __restrict__ y, float* __restrict__ out,
    int posBase, int posEnd, int E) {
    constexpr int G = OUT_C / 4;
    const int lane = threadIdx.x & 63;
    const int wv = (blockIdx.x * blockDim.x + threadIdx.x) >> 6;
    const int g = lane / G, og = lane % G;
    constexpr int S = 64 / G;
    int e = wv * S + g;
    if (e >= E) return;
    float4 acc = make_float4(0.f, 0.f, 0.f, 0.f);
    bool any = false;
#pragma unroll
    for (int s = 0; s < 8; ++s) {
        int q = posOf[e * 8 + s];
        if (q >= posBase && q < posEnd) {
            float4 v = ((const float4*)y)[(size_t)(q - posBase) * G + og];
            acc.x += v.x; acc.y += v.y; acc.z += v.z; acc.w += v.w;
            any = true;
        }
    }
    if (any) {
        float* o = out + (size_t)dst[e] * OUT_C + 4 * og;
        atomicAdd(o + 0, acc.x);
        atomicAdd(o + 1, acc.y);
        atomicAdd(o + 2, acc.z);
        atomicAdd(o + 3, acc.w);
    }
}

// ---------------------------------------------------------------------------
// Legacy edge-centric conv (conv1 in_c=1; also full fallback if ws tiny)
// ---------------------------------------------------------------------------
template <int IN_C, int OUT_C>
__global__ __launch_bounds__(256) void conv_edges(
    const float* __restrict__ x, const int* __restrict__ src,
    const int* __restrict__ dst, const float* __restrict__ basis,
    const int* __restrict__ widx, const float* __restrict__ W,
    float* __restrict__ out, int E) {
    const int lane = threadIdx.x & 63;
    const int wid = threadIdx.x >> 6;
    constexpr int EPW = 64 / OUT_C;
    const int sub = (EPW == 2) ? (lane >> 5) : 0;
    const int o = lane & (OUT_C - 1);
    long e = (long)(blockIdx.x * (blockDim.x >> 6) + wid) * EPW + sub;
    if (e >= E) return;
    const int s_ = src[e];
    const int d_ = dst[e];
    float xv = (o < IN_C) ? x[s_ * IN_C + o] : 0.f;
    float acc = 0.f;
#pragma unroll
    for (int s = 0; s < 8; ++s) {
        const float b = basis[e * 8 + s];
        const int k = widx[e * 8 + s];
        const float* Wk = W + (long)k * IN_C * OUT_C;
#pragma unroll 4
        for (int i = 0; i < IN_C; ++i) {
            float xi = __shfl(xv, i, OUT_C);
            acc = fmaf(b * xi, Wk[i * OUT_C + o], acc);
        }
    }
    atomicAdd(&out[(long)d_ * OUT_C + o], acc);
}

// ---------------------------------------------------------------------------
// Finalize: out = scatter/max(deg,1) + x@R + B, then ELU. In-place.
// ---------------------------------------------------------------------------
template <int IN_C, int OUT_C>
__global__ __launch_bounds__(256) void finalize_k(
    const float* __restrict__ xin, const float* __restrict__ R,
    const float* __restrict__ B, const float* __restrict__ deg,
    float* __restrict__ out, int n) {
    const int lane = threadIdx.x & 63;
    const int wid = threadIdx.x >> 6;
    constexpr int EPW = 64 / OUT_C;
    const int sub = (EPW == 2) ? (lane >> 5) : 0;
    const int o = lane & (OUT_C - 1);
    int j = (blockIdx.x * (blockDim.x >> 6) + wid) * EPW + sub;
    if (j >= n) return;
    float xv = (o < IN_C) ? xin[j * IN_C + o] : 0.f;
    float acc = B[o];
#pragma unroll 4
    for (int i = 0; i < IN_C; ++i) {
        float xi = __shfl(xv, i, OUT_C);
        acc = fmaf(xi, R[i * OUT_C + o], acc);
    }
    float d = fmaxf(deg[j], 1.f);
    float v = out[j * OUT_C + o] / d + acc;
    out[j * OUT_C + o] = (v > 0.f) ? v : expm1f(v);
}

// ---------------------------------------------------------------------------
// Segment max pooling (monotone uint atomicMax; every slot provably written)
// ---------------------------------------------------------------------------
__global__ void pool_scatter(const float* __restrict__ h, const int* __restrict__ cluster,
                             unsigned* __restrict__ pool, int n, int logC) {
    int idx = blockIdx.x * blockDim.x + threadIdx.x;
    if (idx >= (n << logC)) return;
    int j = idx >> logC;
    int c = idx & ((1 << logC) - 1);
    float f = h[idx];
    int b = __float_as_int(f);
    unsigned enc = (b >= 0) ? ((unsigned)b | 0x80000000u) : ~((unsigned)b);
    atomicMax(&pool[(cluster[j] << logC) + c], enc);
}

__global__ void pool_decode(const unsigned* __restrict__ pool, float* __restrict__ out, int total) {
    int idx = blockIdx.x * blockDim.x + threadIdx.x;
    if (idx >= total) return;
    unsigned u = pool[idx];
    int b = (u & 0x80000000u) ? (int)(u & 0x7FFFFFFFu) : (int)(~u);
    out[idx] = __int_as_float(b);
}

// ---------------------------------------------------------------------------
// Head: mean(64x64) -> fc1 -> fc2 -> log_softmax
// ---------------------------------------------------------------------------
__global__ void head_kernel(const float* __restrict__ h, const float* __restrict__ fc1w,
                            const float* __restrict__ fc1b, const float* __restrict__ fc2w,
                            const float* __restrict__ fc2b, float* __restrict__ out) {
    __shared__ float m[64], t[64], u[10];
    int lane = threadIdx.x;
    float s = 0.f;
    for (int j = 0; j < 64; ++j) s += h[j * 64 + lane];
    m[lane] = s * (1.f / 64.f);
    __syncthreads();
    float a = fc1b[lane];
    for (int i = 0; i < 64; ++i) a = fmaf(m[i], fc1w[i * 64 + lane], a);
    t[lane] = a;
    __syncthreads();
    if (lane < 10) {
        float b = fc2b[lane];
        for (int i = 0; i < 64; ++i) b = fmaf(t[i], fc2w[i * 10 + lane], b);
        u[lane] = b;
    }
    __syncthreads();
    if (lane < 10) {
        float mx = u[0];
        for (int i = 1; i < 10; ++i) mx = fmaxf(mx, u[i]);
        float se = 0.f;
        for (int i = 0; i < 10; ++i) se += expf(u[i] - mx);
        out[lane] = u[lane] - mx - logf(se);
    }
}

// ---------------------------------------------------------------------------
// Host side
// ---------------------------------------------------------------------------
static inline int cdiv(int a, int b) { return (a + b - 1) / b; }

struct Ctx {
    float* basis; int* widx; float* deg;
    int* sorted; int* posOf; int* hist; int* cur; int* tileOf;
    float* y; size_t yBytes;
    bool haveSort;
};

template <int IN_C, int OUT_C>
static void run_conv(const float* xin, float* xout, const float* W, const float* R,
                     const float* B, const int* src, const int* dst, int E, int n,
                     const Ctx& c, hipStream_t stream) {
    const int TB = 256;
    hipMemsetAsync(xout, 0, (size_t)n * OUT_C * 4, stream);
    int P = E * 8;
    if (c.haveSort) {
        int TTmax = P / TILE + K3 + 1;
        int CT = (int)(c.yBytes / ((size_t)TILE * OUT_C * 4));
        if (CT > 4096) CT = 4096;
        constexpr int S = 256 / OUT_C;  // edges per wave in phaseB
        for (int cb = 0; cb < TTmax; cb += CT) {
            int ce = (cb + CT < TTmax) ? cb + CT : TTmax;
            gemv_k<IN_C, OUT_C><<<cdiv(ce - cb, 2), 128, 0, stream>>>(
                xin, src, c.basis, c.sorted, c.tileOf, W, c.y, cb, ce);
            phaseB<OUT_C><<<cdiv(cdiv(E, S), 4), TB, 0, stream>>>(
                dst, c.posOf, c.y, xout, cb * TILE, ce * TILE, E);
        }
    } else {
        constexpr int EPW = 64 / OUT_C;
        conv_edges<IN_C, OUT_C><<<cdiv(E, 4 * EPW), TB, 0, stream>>>(
            xin, src, dst, c.basis, c.widx, W, xout, E);
    }
    constexpr int EPW = 64 / OUT_C;
    finalize_k<IN_C, OUT_C><<<cdiv(n, 4 * EPW), TB, 0, stream>>>(xin, R, B, c.deg, xout, n);
}

extern "C" void kernel_launch(void* const* d_in, const int* in_sizes, int n_in,
                              void* d_out, int out_size, void* d_ws, size_t ws_size,
                              hipStream_t stream) {
    const float* x = (const float*)d_in[0];
    const int* src[4] = {(const int*)d_in[1], (const int*)d_in[5], (const int*)d_in[9], (const int*)d_in[13]};
    const int* dst[4] = {(const int*)d_in[2], (const int*)d_in[6], (const int*)d_in[10], (const int*)d_in[14]};
    const float* pseudo[4] = {(const float*)d_in[3], (const float*)d_in[7], (const float*)d_in[11], (const float*)d_in[15]};
    const int* cluster[4] = {(const int*)d_in[4], (const int*)d_in[8], (const int*)d_in[12], (const int*)d_in[16]};
    const float* Wp[8], *Rp[8], *Bp[8];
    for (int l = 0; l < 8; ++l) {
        Wp[l] = (const float*)d_in[17 + 3 * l];
        Rp[l] = (const float*)d_in[18 + 3 * l];
        Bp[l] = (const float*)d_in[19 + 3 * l];
    }
    const float* fc1w = (const float*)d_in[41];
    const float* fc1b = (const float*)d_in[42];
    const float* fc2w = (const float*)d_in[43];
    const float* fc2b = (const float*)d_in[44];
    float* outp = (float*)d_out;

    const int NS[5] = {16384, 4096, 1024, 256, 64};
    const int ES[4] = {16384 * 8, 4096 * 8, 1024 * 8, 256 * 8};
    const int PMAX = ES[0] * 8;                 // 1,048,576
    const int TTMAX0 = PMAX / TILE + K3 + 1;    // worst-case padded tiles

    char* w = (char*)d_ws;
    auto take = [&](size_t bytes) -> char* {
        char* r = w;
        w += (bytes + 255) & ~(size_t)255;
        return r;
    };
    Ctx c;
    c.basis = (float*)take((size_t)PMAX * 4);
    c.widx = (int*)take((size_t)PMAX * 4);
    c.deg = (float*)take((size_t)NS[0] * 4);
    float* bufA = (float*)take((size_t)NS[0] * 64 * 4);
    float* bufB = (float*)take((size_t)NS[0] * 64 * 4);
    unsigned* pool = (unsigned*)take((size_t)NS[1] * 64 * 4);
    c.sorted = (int*)take((size_t)TTMAX0 * TILE * 4);
    c.posOf = (int*)take((size_t)PMAX * 4);
    c.hist = (int*)take((size_t)NHIST * 4);
    c.cur = (int*)take((size_t)NHIST * 4);
    c.tileOf = (int*)take((size_t)TTMAX0 * 4);
    size_t fixedBytes = (size_t)(w - (char*)d_ws);
    c.haveSort = ws_size > fixedBytes + (2u << 20);
    c.y = (float*)w;
    c.yBytes = c.haveSort ? (ws_size - fixedBytes) : 0;
    if (c.yBytes > (32u << 20)) c.yBytes = (32u << 20);

    const int TB = 256;

    auto level_pre = [&](int l) {
        int E = ES[l], P = E * 8, n = NS[l];
        basis_kernel<<<cdiv(E, TB), TB, 0, stream>>>(pseudo[l], c.basis, c.widx, E);
        hipMemsetAsync(c.deg, 0, n * 4, stream);
        deg_kernel<<<cdiv(E, TB), TB, 0, stream>>>(dst[l], c.deg, E);
        if (c.haveSort) {
            int TTmax = P / TILE + K3 + 1;
            hipMemsetAsync(c.hist, 0, NHIST * 4, stream);
            hipMemsetAsync(c.tileOf, 0xFF, (size_t)TTmax * 4, stream);
            hipMemsetAsync(c.sorted, 0xFF, (size_t)TTmax * TILE * 4, stream);
            hist_kernel<<<cdiv(P, TB), TB, 0, stream>>>(c.widx, c.hist, P);
            scan_pad_kernel<<<1, 128, 0, stream>>>(c.hist, c.cur, c.tileOf);
            scatter_kernel<<<cdiv(P, TB), TB, 0, stream>>>(c.widx, c.cur, c.sorted, c.posOf, P);
        }
    };

    // ===== Level 0: n=16384, conv1 (1->32 legacy: W row tiny), conv12 (32->32)
    {
        int E = ES[0], n = NS[0];
        level_pre(0);
        hipMemsetAsync(bufA, 0, (size_t)n * 32 * 4, stream);
        conv_edges<1, 32><<<cdiv(E, 8), TB, 0, stream>>>(x, src[0], dst[0], c.basis, c.widx, Wp[0], bufA, E);
        finalize_k<1, 32><<<cdiv(n, 8), TB, 0, stream>>>(x, Rp[0], Bp[0], c.deg, bufA, n);
        run_conv<32, 32>(bufA, bufB, Wp[1], Rp[1], Bp[1], src[0], dst[0], E, n, c, stream);
        hipMemsetAsync(pool, 0, (size_t)NS[1] * 32 * 4, stream);
        pool_scatter<<<cdiv(n * 32, TB), TB, 0, stream>>>(bufB, cluster[0], pool, n, 5);
        pool_decode<<<cdiv(NS[1] * 32, TB), TB, 0, stream>>>(pool, bufA, NS[1] * 32);
    }
    // ===== Level 1: n=4096, conv2 (32->64), conv3 (64->64)
    {
        int E = ES[1], n = NS[1];
        level_pre(1);
        run_conv<32, 64>(bufA, bufB, Wp[2], Rp[2], Bp[2], src[1], dst[1], E, n, c, stream);
        run_conv<64, 64>(bufB, bufA, Wp[3], Rp[3], Bp[3], src[1], dst[1], E, n, c, stream);
        hipMemsetAsync(pool, 0, (size_t)NS[2] * 64 * 4, stream);
        pool_scatter<<<cdiv(n * 64, TB), TB, 0, stream>>>(bufA, cluster[1], pool, n, 6);
        pool_decode<<<cdiv(NS[2] * 64, TB), TB, 0, stream>>>(pool, bufB, NS[2] * 64);
    }
    // ===== Level 2: n=1024
    {
        int E = ES[2], n = NS[2];
        level_pre(2);
        run_conv<64, 64>(bufB, bufA, Wp[4], Rp[4], Bp[4], src[2], dst[2], E, n, c, stream);
        run_conv<64, 64>(bufA, bufB, Wp[5], Rp[5], Bp[5], src[2], dst[2], E, n, c, stream);
        hipMemsetAsync(pool, 0, (size_t)NS[3] * 64 * 4, stream);
        pool_scatter<<<cdiv(n * 64, TB), TB, 0, stream>>>(bufB, cluster[2], pool, n, 6);
        pool_decode<<<cdiv(NS[3] * 64, TB), TB, 0, stream>>>(pool, bufA, NS[3] * 64);
    }
    // ===== Level 3: n=256
    {
        int E = ES[3], n = NS[3];
        level_pre(3);
        run_conv<64, 64>(bufA, bufB, Wp[6], Rp[6], Bp[6], src[3], dst[3], E, n, c, stream);
        run_conv<64, 64>(bufB, bufA, Wp[7], Rp[7], Bp[7], src[3], dst[3], E, n, c, stream);
        hipMemsetAsync(pool, 0, (size_t)NS[4] * 64 * 4, stream);
        pool_scatter<<<cdiv(n * 64, TB), TB, 0, stream>>>(bufA, cluster[3], pool, n, 6);
        pool_decode<<<cdiv(NS[4] * 64, TB), TB, 0, stream>>>(pool, bufB, NS[4] * 64);
    }
    // ===== Head
    head_kernel<<<1, 64, 0, stream>>>(bufB, fc1w, fc1b, fc2w, fc2b, outp);
}

// Round 4
// 860.015 us; speedup vs baseline: 1.6758x; 1.6758x over previous
//
#include <hip/hip_runtime.h>
#include <hip/hip_bf16.h>

#define KS 5
#define K3 125
#define PADW 65

// ---------------------------------------------------------------------------
// Inline basis: degree-1 open B-spline, 8 (weight,index) pairs per edge
// ---------------------------------------------------------------------------
__device__ inline void edge_basis(const float* __restrict__ pseudo, int e,
                                  float* bs, int* ks) {
    float fr[3];
    int bot[3];
#pragma unroll
    for (int d = 0; d < 3; ++d) {
        float v = pseudo[e * 3 + d] * (float)(KS - 1);
        float fl = fminf(floorf(v), (float)(KS - 2));
        fr[d] = v - fl;
        bot[d] = (int)fl;
    }
    const int strides[3] = {1, KS, KS * KS};
#pragma unroll
    for (int s = 0; s < 8; ++s) {
        float b = 1.f;
        int w = 0;
#pragma unroll
        for (int d = 0; d < 3; ++d) {
            int bit = (s >> d) & 1;
            b *= bit ? fr[d] : (1.f - fr[d]);
            w += (bot[d] + bit) * strides[d];
        }
        bs[s] = b;
        ks[s] = w;
    }
}

__global__ void deg_kernel(const int* __restrict__ dst, float* __restrict__ deg, int E) {
    int e = blockIdx.x * blockDim.x + threadIdx.x;
    if (e >= E) return;
    atomicAdd(&deg[dst[e]], 1.0f);
}

// ---------------------------------------------------------------------------
// Pass 1: per-level k histogram (LDS-aggregated, one global atomic per bucket
// per block). Basis recomputed inline — no basis/widx arrays.
// ---------------------------------------------------------------------------
__global__ __launch_bounds__(256) void hist_pairs(const float* __restrict__ pseudo,
                                                  int* __restrict__ hist, int E) {
    __shared__ int h[K3];
    int t = threadIdx.x;
    if (t < K3) h[t] = 0;
    __syncthreads();
    int e = blockIdx.x * 256 + t;
    if (e < E) {
        float bs[8];
        int ks[8];
        edge_basis(pseudo, e, bs, ks);
#pragma unroll
        for (int s = 0; s < 8; ++s) atomicAdd(&h[ks[s]], 1);
    }
    __syncthreads();
    if (t < K3 && h[t]) atomicAdd(&hist[t], h[t]);
}

// ---------------------------------------------------------------------------
// Pass 2: per-level bucket layout. Tiles of 64 entries, padded per bucket.
// Writes entry cursors (gcur), pad ranges, and tile->k map.
// One block of 128 threads per level.
// ---------------------------------------------------------------------------
__global__ void scan_pad(const int* __restrict__ hist, int* __restrict__ gcur,
                         int* __restrict__ padS, int* __restrict__ padE,
                         int* __restrict__ tileOf, int tileBase) {
    __shared__ int sh[128];
    int t = threadIdx.x;
    int cnt = (t < K3) ? hist[t] : 0;
    int tiles = (cnt + 63) >> 6;
    sh[t] = tiles;
    __syncthreads();
    for (int d = 1; d < 128; d <<= 1) {
        int v = (t >= d) ? sh[t - d] : 0;
        __syncthreads();
        sh[t] += v;
        __syncthreads();
    }
    if (t < K3) {
        int tb = tileBase + sh[t] - tiles;
        int eb = tb * 64;
        gcur[t] = eb;
        padS[t] = eb + cnt;
        padE[t] = eb + tiles * 64;
        for (int q = 0; q < tiles; ++q) tileOf[tb + q] = t;
    }
}

// Fill pad slots with (p=-1, b=0). 125 blocks x 64 threads per level.
__global__ void pad_fill(const int* __restrict__ padS, const int* __restrict__ padE,
                         int2* __restrict__ pack) {
    int k = blockIdx.x;
    for (int idx = padS[k] + threadIdx.x; idx < padE[k]; idx += 64)
        pack[idx] = make_int2(-1, 0);
}

// ---------------------------------------------------------------------------
// Pass 3: block-local counting sort. Block = 256 edges = 2048 pairs.
// LDS bucket by k, reserve per-bucket global runs via one atomicAdd each,
// then burst-copy (p, basis) int2 entries out run-wise (coalesced).
// ---------------------------------------------------------------------------
__global__ __launch_bounds__(256) void scatter_local(const float* __restrict__ pseudo,
                                                     int* __restrict__ gcur,
                                                     int2* __restrict__ pack, int E) {
    __shared__ int h[K3], lb[K3], gb[K3];
    __shared__ int sh[128];
    __shared__ int sp[2048];
    __shared__ float sb[2048];
    __shared__ unsigned char skk[2048];
    int t = threadIdx.x;
    int e = blockIdx.x * 256 + t;
    bool val = e < E;
    float bs[8];
    int ks[8];
    if (val) edge_basis(pseudo, e, bs, ks);
    if (t < K3) h[t] = 0;
    __syncthreads();
    if (val)
#pragma unroll
        for (int s = 0; s < 8; ++s) atomicAdd(&h[ks[s]], 1);
    __syncthreads();
    if (t < 128) sh[t] = (t < K3) ? h[t] : 0;
    __syncthreads();
    for (int d = 1; d < 128; d <<= 1) {
        int v = (t < 128 && t >= d) ? sh[t - d] : 0;
        __syncthreads();
        if (t < 128) sh[t] += v;
        __syncthreads();
    }
    if (t < K3) {
        int c = h[t];
        lb[t] = sh[t] - c;
        gb[t] = c ? atomicAdd(&gcur[t], c) : 0;
        h[t] = 0;  // reuse as local cursor
    }
    __syncthreads();
    if (val)
#pragma unroll
        for (int s = 0; s < 8; ++s) {
            int k = ks[s];
            int pos = lb[k] + atomicAdd(&h[k], 1);
            sp[pos] = e * 8 + s;
            sb[pos] = bs[s];
            skk[pos] = (unsigned char)k;
        }
    __syncthreads();
    int Pb = (E - blockIdx.x * 256);
    Pb = (Pb > 256 ? 256 : Pb) * 8;
    for (int j = t; j < Pb; j += 256) {
        int k = skk[j];
        int g = gb[k] + (j - lb[k]);
        pack[g] = make_int2(sp[j], __float_as_int(sb[j]));
    }
}

// ---------------------------------------------------------------------------
// Fused conv1 (in_c = 1): per edge, acc_o = sum_s b_s W[k_s][o]; out += acc*x.
// ---------------------------------------------------------------------------
__global__ __launch_bounds__(256) void conv1_fused(const float* __restrict__ x,
                                                   const int* __restrict__ src,
                                                   const int* __restrict__ dst,
                                                   const float* __restrict__ pseudo,
                                                   const float* __restrict__ W,
                                                   float* __restrict__ out, int E) {
    const int lane = threadIdx.x & 63;
    const int wid = threadIdx.x >> 6;
    const int sub = lane >> 5;
    const int o = lane & 31;
    int e = (blockIdx.x * 4 + wid) * 2 + sub;
    if (e >= E) return;
    float bs[8];
    int ks[8];
    edge_basis(pseudo, e, bs, ks);
    float acc = 0.f;
#pragma unroll
    for (int s = 0; s < 8; ++s) acc = fmaf(bs[s], W[ks[s] * 32 + o], acc);
    atomicAdd(&out[(size_t)dst[e] * 32 + o], acc * x[src[e]]);
}

// ---------------------------------------------------------------------------
// Fused GEMV+scatter over k-uniform 64-pair tiles. lane = pair.
// xT staged in LDS (basis-prescaled); W via wave-uniform (scalar) loads
// broadcast through the SGPR fma operand; epilogue LDS-transposes and issues
// coalesced 32-lane atomic bursts directly into out[dst].
// ---------------------------------------------------------------------------
__device__ inline void flush32(float* xT, const float* a, int m, int dn,
                               float* __restrict__ out, int OUT_C, int obase) {
#pragma unroll
    for (int oo = 0; oo < 32; ++oo) xT[oo * PADW + m] = a[oo];
    const int o = m & 31, rh = m >> 5;
    for (int it = 0; it < 32; ++it) {
        int r = 2 * it + rh;
        int dr = __shfl(dn, r);
        if (dr >= 0) atomicAdd(&out[(size_t)dr * OUT_C + obase + o], xT[o * PADW + r]);
    }
}

template <int IN_C, int OUT_C>
__global__ __launch_bounds__(128) void gemv_scatter(
    const float* __restrict__ x, const int* __restrict__ src,
    const int* __restrict__ dst, const int2* __restrict__ pack,
    const int* __restrict__ tileOf, const float* __restrict__ W,
    float* __restrict__ out, int tileBase, int nTiles) {
    constexpr int XR = (IN_C > 32) ? IN_C : 32;
    __shared__ float lds[2 * XR * PADW];
    const int wid = threadIdx.x >> 6;
    const int m = threadIdx.x & 63;
    float* xT = &lds[wid * XR * PADW];
    int ti = blockIdx.x * 2 + wid;
    if (ti >= nTiles) return;
    int t = tileBase + ti;
    int k = tileOf[t];
    if (k < 0) return;
    k = __builtin_amdgcn_readfirstlane(k);
    int2 en = pack[(size_t)t * 64 + m];
    int p = en.x;
    float b = (p >= 0) ? __int_as_float(en.y) : 0.f;
    int e = p >> 3;
    int sn = (p >= 0) ? src[e] : 0;
    int dn = (p >= 0) ? dst[e] : -1;
    // stage xT[i][r] = x[src_r][i] * b_r
    constexpr int RPI = 64 / IN_C;
    const int i0 = m % IN_C;
    const int rofs = m / IN_C;
    for (int r = rofs; r < 64; r += RPI) {
        int sr = __shfl(sn, r);
        float br = __shfl(b, r);
        xT[i0 * PADW + r] = x[(size_t)sr * IN_C + i0] * br;
    }
    const float* __restrict__ Wk = W + (size_t)k * IN_C * OUT_C;
    float a0[32];
#pragma unroll
    for (int oo = 0; oo < 32; ++oo) a0[oo] = 0.f;
    for (int i = 0; i < IN_C; ++i) {
        float xv = xT[i * PADW + m];
#pragma unroll
        for (int oo = 0; oo < 32; ++oo) a0[oo] = fmaf(Wk[i * OUT_C + oo], xv, a0[oo]);
    }
    if constexpr (OUT_C == 64) {
        float a1[32];
#pragma unroll
        for (int oo = 0; oo < 32; ++oo) a1[oo] = 0.f;
        for (int i = 0; i < IN_C; ++i) {
            float xv = xT[i * PADW + m];
#pragma unroll
            for (int oo = 0; oo < 32; ++oo)
                a1[oo] = fmaf(Wk[i * OUT_C + 32 + oo], xv, a1[oo]);
        }
        flush32(xT, a0, m, dn, out, OUT_C, 0);
        flush32(xT, a1, m, dn, out, OUT_C, 32);
    } else {
        flush32(xT, a0, m, dn, out, OUT_C, 0);
    }
}

// ---------------------------------------------------------------------------
// Finalize: out = scatter/max(deg,1) + x@R + B, then ELU. In-place.
// ---------------------------------------------------------------------------
template <int IN_C, int OUT_C>
__global__ __launch_bounds__(256) void finalize_k(
    const float* __restrict__ xin, const float* __restrict__ R,
    const float* __restrict__ B, const float* __restrict__ deg,
    float* __restrict__ out, int n) {
    const int lane = threadIdx.x & 63;
    const int wid = threadIdx.x >> 6;
    constexpr int EPW = 64 / OUT_C;
    const int sub = (EPW == 2) ? (lane >> 5) : 0;
    const int o = lane & (OUT_C - 1);
    int j = (blockIdx.x * (blockDim.x >> 6) + wid) * EPW + sub;
    if (j >= n) return;
    float xv = (o < IN_C) ? xin[j * IN_C + o] : 0.f;
    float acc = B[o];
#pragma unroll 4
    for (int i = 0; i < IN_C; ++i) {
        float xi = __shfl(xv, i, OUT_C);
        acc = fmaf(xi, R[i * OUT_C + o], acc);
    }
    float d = fmaxf(deg[j], 1.f);
    float v = out[j * OUT_C + o] / d + acc;
    out[j * OUT_C + o] = (v > 0.f) ? v : expm1f(v);
}

// ---------------------------------------------------------------------------
// Legacy path (ws-too-small fallback)
// ---------------------------------------------------------------------------
__global__ void basis_kernel(const float* __restrict__ pseudo,
                             float* __restrict__ basis, int* __restrict__ widx, int E) {
    int e = blockIdx.x * blockDim.x + threadIdx.x;
    if (e >= E) return;
    float bs[8];
    int ks[8];
    edge_basis(pseudo, e, bs, ks);
#pragma unroll
    for (int s = 0; s < 8; ++s) {
        basis[e * 8 + s] = bs[s];
        widx[e * 8 + s] = ks[s];
    }
}

template <int IN_C, int OUT_C>
__global__ __launch_bounds__(256) void conv_edges(
    const float* __restrict__ x, const int* __restrict__ src,
    const int* __restrict__ dst, const float* __restrict__ basis,
    const int* __restrict__ widx, const float* __restrict__ W,
    float* __restrict__ out, int E) {
    const int lane = threadIdx.x & 63;
    const int wid = threadIdx.x >> 6;
    constexpr int EPW = 64 / OUT_C;
    const int sub = (EPW == 2) ? (lane >> 5) : 0;
    const int o = lane & (OUT_C - 1);
    long e = (long)(blockIdx.x * (blockDim.x >> 6) + wid) * EPW + sub;
    if (e >= E) return;
    const int s_ = src[e];
    const int d_ = dst[e];
    float xv = (o < IN_C) ? x[s_ * IN_C + o] : 0.f;
    float acc = 0.f;
#pragma unroll
    for (int s = 0; s < 8; ++s) {
        const float b = basis[e * 8 + s];
        const int k = widx[e * 8 + s];
        const float* Wk = W + (long)k * IN_C * OUT_C;
#pragma unroll 4
        for (int i = 0; i < IN_C; ++i) {
            float xi = __shfl(xv, i, OUT_C);
            acc = fmaf(b * xi, Wk[i * OUT_C + o], acc);
        }
    }
    atomicAdd(&out[(long)d_ * OUT_C + o], acc);
}

// ---------------------------------------------------------------------------
// Segment max pooling (monotone uint atomicMax; every slot provably written)
// ---------------------------------------------------------------------------
__global__ void pool_scatter(const float* __restrict__ h, const int* __restrict__ cluster,
                             unsigned* __restrict__ pool, int n, int logC) {
    int idx = blockIdx.x * blockDim.x + threadIdx.x;
    if (idx >= (n << logC)) return;
    int j = idx >> logC;
    int c = idx & ((1 << logC) - 1);
    float f = h[idx];
    int b = __float_as_int(f);
    unsigned enc = (b >= 0) ? ((unsigned)b | 0x80000000u) : ~((unsigned)b);
    atomicMax(&pool[(cluster[j] << logC) + c], enc);
}

__global__ void pool_decode(const unsigned* __restrict__ pool, float* __restrict__ out, int total) {
    int idx = blockIdx.x * blockDim.x + threadIdx.x;
    if (idx >= total) return;
    unsigned u = pool[idx];
    int b = (u & 0x80000000u) ? (int)(u & 0x7FFFFFFFu) : (int)(~u);
    out[idx] = __int_as_float(b);
}

// ---------------------------------------------------------------------------
// Head: mean(64x64) -> fc1 -> fc2 -> log_softmax
// ---------------------------------------------------------------------------
__global__ void head_kernel(const float* __restrict__ h, const float* __restrict__ fc1w,
                            const float* __restrict__ fc1b, const float* __restrict__ fc2w,
                            const float* __restrict__ fc2b, float* __restrict__ out) {
    __shared__ float m[64], t[64], u[10];
    int lane = threadIdx.x;
    float s = 0.f;
    for (int j = 0; j < 64; ++j) s += h[j * 64 + lane];
    m[lane] = s * (1.f / 64.f);
    __syncthreads();
    float a = fc1b[lane];
    for (int i = 0; i < 64; ++i) a = fmaf(m[i], fc1w[i * 64 + lane], a);
    t[lane] = a;
    __syncthreads();
    if (lane < 10) {
        float b = fc2b[lane];
        for (int i = 0; i < 64; ++i) b = fmaf(t[i], fc2w[i * 10 + lane], b);
        u[lane] = b;
    }
    __syncthreads();
    if (lane < 10) {
        float mx = u[0];
        for (int i = 1; i < 10; ++i) mx = fmaxf(mx, u[i]);
        float se = 0.f;
        for (int i = 0; i < 10; ++i) se += expf(u[i] - mx);
        out[lane] = u[lane] - mx - logf(se);
    }
}

// ---------------------------------------------------------------------------
// Host side
// ---------------------------------------------------------------------------
static inline int cdiv(int a, int b) { return (a + b - 1) / b; }

extern "C" void kernel_launch(void* const* d_in, const int* in_sizes, int n_in,
                              void* d_out, int out_size, void* d_ws, size_t ws_size,
                              hipStream_t stream) {
    const float* x = (const float*)d_in[0];
    const int* src[4] = {(const int*)d_in[1], (const int*)d_in[5], (const int*)d_in[9], (const int*)d_in[13]};
    const int* dst[4] = {(const int*)d_in[2], (const int*)d_in[6], (const int*)d_in[10], (const int*)d_in[14]};
    const float* pseudo[4] = {(const float*)d_in[3], (const float*)d_in[7], (const float*)d_in[11], (const float*)d_in[15]};
    const int* cluster[4] = {(const int*)d_in[4], (const int*)d_in[8], (const int*)d_in[12], (const int*)d_in[16]};
    const float* Wp[8], *Rp[8], *Bp[8];
    for (int l = 0; l < 8; ++l) {
        Wp[l] = (const float*)d_in[17 + 3 * l];
        Rp[l] = (const float*)d_in[18 + 3 * l];
        Bp[l] = (const float*)d_in[19 + 3 * l];
    }
    const float* fc1w = (const float*)d_in[41];
    const float* fc1b = (const float*)d_in[42];
    const float* fc2w = (const float*)d_in[43];
    const float* fc2b = (const float*)d_in[44];
    float* outp = (float*)d_out;

    const int NS[5] = {16384, 4096, 1024, 256, 64};
    const int ES[4] = {16384 * 8, 4096 * 8, 1024 * 8, 256 * 8};
    // static tile layout: per level P/64 + 125 tiles
    const int MT[4] = {16384 + 125, 4096 + 125, 1024 + 125, 256 + 125};
    const int TB_[4] = {0, 16509, 16509 + 4221, 16509 + 4221 + 1149};
    const int TOT_TILES = 16509 + 4221 + 1149 + 381;  // 22260
    const int PMAX = ES[0] * 8;

    char* w = (char*)d_ws;
    auto take = [&](size_t bytes) -> char* {
        char* r = w;
        w += (bytes + 255) & ~(size_t)255;
        return r;
    };
    int2* pack = (int2*)take((size_t)TOT_TILES * 64 * 8);  // 11.4 MB
    float* bufA = (float*)take((size_t)NS[0] * 64 * 4);    // 4 MB
    float* bufB = (float*)take((size_t)NS[0] * 64 * 4);    // 4 MB
    unsigned* pool = (unsigned*)take((size_t)NS[1] * 64 * 4);  // 1 MB
    float* deg = (float*)take((size_t)NS[0] * 4);
    int* hist = (int*)take((size_t)4 * K3 * 4);
    int* gcur = (int*)take((size_t)4 * K3 * 4);
    int* padS = (int*)take((size_t)4 * K3 * 4);
    int* padE = (int*)take((size_t)4 * K3 * 4);
    int* tileOf = (int*)take((size_t)TOT_TILES * 4);
    size_t need = (size_t)(w - (char*)d_ws);
    bool fast = ws_size >= need;

    const int TB = 256;

    if (fast) {
        // ---------- preprocessing: one combined sort, all levels ----------
        hipMemsetAsync(hist, 0, 4 * K3 * 4, stream);
        hipMemsetAsync(tileOf, 0xFF, (size_t)TOT_TILES * 4, stream);
        for (int l = 0; l < 4; ++l)
            hist_pairs<<<cdiv(ES[l], TB), TB, 0, stream>>>(pseudo[l], hist + l * K3, ES[l]);
        for (int l = 0; l < 4; ++l)
            scan_pad<<<1, 128, 0, stream>>>(hist + l * K3, gcur + l * K3, padS + l * K3,
                                            padE + l * K3, tileOf, TB_[l]);
        for (int l = 0; l < 4; ++l)
            pad_fill<<<K3, 64, 0, stream>>>(padS + l * K3, padE + l * K3, pack);
        for (int l = 0; l < 4; ++l)
            scatter_local<<<cdiv(ES[l], 256), 256, 0, stream>>>(pseudo[l], gcur + l * K3,
                                                                pack, ES[l]);

        // ---------------- Level 0: conv1 (1->32), conv12 (32->32) ----------
        {
            int E = ES[0], n = NS[0];
            hipMemsetAsync(deg, 0, n * 4, stream);
            deg_kernel<<<cdiv(E, TB), TB, 0, stream>>>(dst[0], deg, E);
            hipMemsetAsync(bufA, 0, (size_t)n * 32 * 4, stream);
            conv1_fused<<<cdiv(E, 8), TB, 0, stream>>>(x, src[0], dst[0], pseudo[0], Wp[0], bufA, E);
            finalize_k<1, 32><<<cdiv(n, 8), TB, 0, stream>>>(x, Rp[0], Bp[0], deg, bufA, n);
            hipMemsetAsync(bufB, 0, (size_t)n * 32 * 4, stream);
            gemv_scatter<32, 32><<<cdiv(MT[0], 2), 128, 0, stream>>>(
                bufA, src[0], dst[0], pack, tileOf, Wp[1], bufB, TB_[0], MT[0]);
            finalize_k<32, 32><<<cdiv(n, 8), TB, 0, stream>>>(bufA, Rp[1], Bp[1], deg, bufB, n);
            hipMemsetAsync(pool, 0, (size_t)NS[1] * 32 * 4, stream);
            pool_scatter<<<cdiv(n * 32, TB), TB, 0, stream>>>(bufB, cluster[0], pool, n, 5);
            pool_decode<<<cdiv(NS[1] * 32, TB), TB, 0, stream>>>(pool, bufA, NS[1] * 32);
        }
        // ---------------- Level 1: conv2 (32->64), conv3 (64->64) ----------
        {
            int E = ES[1], n = NS[1];
            hipMemsetAsync(deg, 0, n * 4, stream);
            deg_kernel<<<cdiv(E, TB), TB, 0, stream>>>(dst[1], deg, E);
            hipMemsetAsync(bufB, 0, (size_t)n * 64 * 4, stream);
            gemv_scatter<32, 64><<<cdiv(MT[1], 2), 128, 0, stream>>>(
                bufA, src[1], dst[1], pack, tileOf, Wp[2], bufB, TB_[1], MT[1]);
            finalize_k<32, 64><<<cdiv(n, 4), TB, 0, stream>>>(bufA, Rp[2], Bp[2], deg, bufB, n);
            hipMemsetAsync(bufA, 0, (size_t)n * 64 * 4, stream);
            gemv_scatter<64, 64><<<cdiv(MT[1], 2), 128, 0, stream>>>(
                bufB, src[1], dst[1], pack, tileOf, Wp[3], bufA, TB_[1], MT[1]);
            finalize_k<64, 64><<<cdiv(n, 4), TB, 0, stream>>>(bufB, Rp[3], Bp[3], deg, bufA, n);
            hipMemsetAsync(pool, 0, (size_t)NS[2] * 64 * 4, stream);
            pool_scatter<<<cdiv(n * 64, TB), TB, 0, stream>>>(bufA, cluster[1], pool, n, 6);
            pool_decode<<<cdiv(NS[2] * 64, TB), TB, 0, stream>>>(pool, bufB, NS[2] * 64);
        }
        // ---------------- Level 2: conv4, conv5 (64->64) -------------------
        {
            int E = ES[2], n = NS[2];
            hipMemsetAsync(deg, 0, n * 4, stream);
            deg_kernel<<<cdiv(E, TB), TB, 0, stream>>>(dst[2], deg, E);
            hipMemsetAsync(bufA, 0, (size_t)n * 64 * 4, stream);
            gemv_scatter<64, 64><<<cdiv(MT[2], 2), 128, 0, stream>>>(
                bufB, src[2], dst[2], pack, tileOf, Wp[4], bufA, TB_[2], MT[2]);
            finalize_k<64, 64><<<cdiv(n, 4), TB, 0, stream>>>(bufB, Rp[4], Bp[4], deg, bufA, n);
            hipMemsetAsync(bufB, 0, (size_t)n * 64 * 4, stream);
            gemv_scatter<64, 64><<<cdiv(MT[2], 2), 128, 0, stream>>>(
                bufA, src[2], dst[2], pack, tileOf, Wp[5], bufB, TB_[2], MT[2]);
            finalize_k<64, 64><<<cdiv(n, 4), TB, 0, stream>>>(bufA, Rp[5], Bp[5], deg, bufB, n);
            hipMemsetAsync(pool, 0, (size_t)NS[3] * 64 * 4, stream);
            pool_scatter<<<cdiv(n * 64, TB), TB, 0, stream>>>(bufB, cluster[2], pool, n, 6);
            pool_decode<<<cdiv(NS[3] * 64, TB), TB, 0, stream>>>(pool, bufA, NS[3] * 64);
        }
        // ---------------- Level 3: conv6, conv7 (64->64) -------------------
        {
            int E = ES[3], n = NS[3];
            hipMemsetAsync(deg, 0, n * 4, stream);
            deg_kernel<<<cdiv(E, TB), TB, 0, stream>>>(dst[3], deg, E);
            hipMemsetAsync(bufB, 0, (size_t)n * 64 * 4, stream);
            gemv_scatter<64, 64><<<cdiv(MT[3], 2), 128, 0, stream>>>(
                bufA, src[3], dst[3], pack, tileOf, Wp[6], bufB, TB_[3], MT[3]);
            finalize_k<64, 64><<<cdiv(n, 4), TB, 0, stream>>>(bufA, Rp[6], Bp[6], deg, bufB, n);
            hipMemsetAsync(bufA, 0, (size_t)n * 64 * 4, stream);
            gemv_scatter<64, 64><<<cdiv(MT[3], 2), 128, 0, stream>>>(
                bufB, src[3], dst[3], pack, tileOf, Wp[7], bufA, TB_[3], MT[3]);
            finalize_k<64, 64><<<cdiv(n, 4), TB, 0, stream>>>(bufB, Rp[7], Bp[7], deg, bufA, n);
            hipMemsetAsync(pool, 0, (size_t)NS[4] * 64 * 4, stream);
            pool_scatter<<<cdiv(n * 64, TB), TB, 0, stream>>>(bufA, cluster[3], pool, n, 6);
            pool_decode<<<cdiv(NS[4] * 64, TB), TB, 0, stream>>>(pool, bufB, NS[4] * 64);
        }
        head_kernel<<<1, 64, 0, stream>>>(bufB, fc1w, fc1b, fc2w, fc2b, outp);
    } else {
        // ---------------- legacy R1 fallback (small ws) --------------------
        float* basis = (float*)pack;
        int* widx = (int*)((char*)pack + (size_t)PMAX * 4);
        const float* cin = nullptr;
        float* h0 = bufA;
        float* h1 = bufB;
        for (int l = 0; l < 4; ++l) {
            int E = ES[l], n = NS[l];
            basis_kernel<<<cdiv(E, TB), TB, 0, stream>>>(pseudo[l], basis, widx, E);
            hipMemsetAsync(deg, 0, n * 4, stream);
            deg_kernel<<<cdiv(E, TB), TB, 0, stream>>>(dst[l], deg, E);
            for (int cc = 0; cc < 2; ++cc) {
                int li = (l == 0) ? cc : 2 * l + cc;
                if (l == 0 && cc == 0) {
                    hipMemsetAsync(h0, 0, (size_t)n * 32 * 4, stream);
                    conv_edges<1, 32><<<cdiv(E, 8), TB, 0, stream>>>(x, src[0], dst[0], basis, widx, Wp[0], h0, E);
                    finalize_k<1, 32><<<cdiv(n, 8), TB, 0, stream>>>(x, Rp[0], Bp[0], deg, h0, n);
                } else {
                    int ic = (l == 0) ? 32 : ((l == 1 && cc == 0) ? 32 : 64);
                    int oc = (l == 0) ? 32 : 64;
                    hipMemsetAsync(h1, 0, (size_t)n * oc * 4, stream);
                    if (ic == 32 && oc == 32) {
                        conv_edges<32, 32><<<cdiv(E, 8), TB, 0, stream>>>(h0, src[l], dst[l], basis, widx, Wp[li], h1, E);
                        finalize_k<32, 32><<<cdiv(n, 8), TB, 0, stream>>>(h0, Rp[li], Bp[li], deg, h1, n);
                    } else if (ic == 32) {
                        conv_edges<32, 64><<<cdiv(E, 4), TB, 0, stream>>>(h0, src[l], dst[l], basis, widx, Wp[li], h1, E);
                        finalize_k<32, 64><<<cdiv(n, 4), TB, 0, stream>>>(h0, Rp[li], Bp[li], deg, h1, n);
                    } else {
                        conv_edges<64, 64><<<cdiv(E, 4), TB, 0, stream>>>(h0, src[l], dst[l], basis, widx, Wp[li], h1, E);
                        finalize_k<64, 64><<<cdiv(n, 4), TB, 0, stream>>>(h0, Rp[li], Bp[li], deg, h1, n);
                    }
                    float* tmp = h0; h0 = h1; h1 = tmp;
                }
            }
            int oc = (l == 0) ? 32 : 64;
            int logC = (l == 0) ? 5 : 6;
            hipMemsetAsync(pool, 0, (size_t)NS[l + 1] * oc * 4, stream);
            pool_scatter<<<cdiv(n * oc, TB), TB, 0, stream>>>(h0, cluster[l], pool, n, logC);
            pool_decode<<<cdiv(NS[l + 1] * oc, TB), TB, 0, stream>>>(pool, h1, NS[l + 1] * oc);
            float* tmp = h0; h0 = h1; h1 = tmp;
        }
        head_kernel<<<1, 64, 0, stream>>>(h0, fc1w, fc1b, fc2w, fc2b, outp);
        (void)cin;
    }
}